// Round 7
// baseline (406.007 us; speedup 1.0000x reference)
//
#include <hip/hip_runtime.h>
#include <math.h>

#define NN 10000       // N_NODES
#define NE 160000      // N_EDGES
#define NG 100         // N_GRAPHS
#define DD 32
#define QQ 96
#define EPS 1e-5f

// ---------------- fused BN stats for BOTH convs' edge-MLPs
// 512 threads, 2 cols per conv per thread. Weight scalars PINNED to VGPRs via
// opaque asm: the allocator cannot rematerialize/spill-reload them per iter
// (R4/R6 pathology: VGPR=28, 20MB scratch writes, 2.7x the VALU floor).
// stats layout: [0..1023] c1 sum | [1024..2047] c1 sumsq | [2048..3071] c2 sum | [3072..4095] c2 sumsq
#define SDECL(P) float P##w0, P##w1, P##w2, P##w3, P##w4, P##w5, P##b, P##s, P##ss;
#define SLOAD(P, wptr, bptr, j) { const float* _wr = (wptr) + (j) * 6; \
    P##w0 = _wr[0]; P##w1 = _wr[1]; P##w2 = _wr[2]; \
    P##w3 = _wr[3]; P##w4 = _wr[4]; P##w5 = _wr[5]; \
    P##b = (bptr)[j]; P##s = 0.f; P##ss = 0.f; }
#define SPIN(P) asm("" : "+v"(P##w0), "+v"(P##w1), "+v"(P##w2), "+v"(P##w3), \
                         "+v"(P##w4), "+v"(P##w5), "+v"(P##b));
#define SACC(P) { float _y = P##b; \
    _y = fmaf(e0, P##w0, _y); _y = fmaf(e1, P##w1, _y); _y = fmaf(e2, P##w2, _y); \
    _y = fmaf(e3, P##w3, _y); _y = fmaf(e4, P##w4, _y); _y = fmaf(e5, P##w5, _y); \
    float _r = fmaxf(_y, 0.f); P##s += _r; P##ss = fmaf(_r, _r, P##ss); }

__global__ __launch_bounds__(512) void k_stats2(const float* __restrict__ ea,
        const float* __restrict__ w1, const float* __restrict__ b1,
        const float* __restrict__ w2, const float* __restrict__ b2,
        float* __restrict__ stats) {
    const int tid = threadIdx.x;
    const int j0 = tid * 2;
    SDECL(a0) SDECL(a1) SDECL(c0) SDECL(c1)
    SLOAD(a0, w1, b1, j0) SLOAD(a1, w1, b1, j0 + 1)
    SLOAD(c0, w2, b2, j0) SLOAD(c1, w2, b2, j0 + 1)
    SPIN(a0) SPIN(a1) SPIN(c0) SPIN(c1)
    const int base = blockIdx.x * 256;   // 625 blocks * 256 edges = NE
#pragma unroll 4
    for (int el = 0; el < 256; ++el) {
        // block-uniform address -> scalar broadcast load
        const float* er = ea + (base + el) * 6;
        float2 p0 = *reinterpret_cast<const float2*>(er);
        float2 p1 = *reinterpret_cast<const float2*>(er + 2);
        float2 p2 = *reinterpret_cast<const float2*>(er + 4);
        float e0 = p0.x, e1 = p0.y, e2 = p1.x, e3 = p1.y, e4 = p2.x, e5 = p2.y;
        SACC(a0) SACC(a1) SACC(c0) SACC(c1)
    }
    atomicAdd(&stats[j0], a0s);           atomicAdd(&stats[j0 + 1], a1s);
    atomicAdd(&stats[1024 + j0], a0ss);   atomicAdd(&stats[1024 + j0 + 1], a1ss);
    atomicAdd(&stats[2048 + j0], c0s);    atomicAdd(&stats[2048 + j0 + 1], c1s);
    atomicAdd(&stats[3072 + j0], c0ss);   atomicAdd(&stats[3072 + j0 + 1], c1ss);
}

// -------- k_root: out[n,o] = bias[o] + x[n]@root.  Block gridDim-1 (optional,
// when doFin!=0) instead computes BOTH convs' BN affines from stats.
// AB layout: [0..1023] A1 | [1024..2047] B1 | [2048..3071] A2 | [3072..4095] B2
__global__ __launch_bounds__(256) void k_root(const float* __restrict__ x,
        const float* __restrict__ root, const float* __restrict__ bias,
        float* __restrict__ out,
        int doFin, const float* __restrict__ stats,
        const float* __restrict__ g1, const float* __restrict__ beta1,
        const float* __restrict__ g2, const float* __restrict__ beta2,
        float* __restrict__ AB) {
    const int tid = threadIdx.x;
    if (doFin && blockIdx.x == gridDim.x - 1) {
        const float invE = 1.f / NE;
        for (int j = tid; j < 2048; j += 256) {
            int cv = j >> 10, col = j & 1023;
            const float* st = stats + cv * 2048;
            const float* g = cv ? g2 : g1;
            const float* bt = cv ? beta2 : beta1;
            float mean = st[col] * invE;
            float var = fmaxf(st[1024 + col] * invE - mean * mean, 0.f);
            float a = g[col] * rsqrtf(var + EPS);
            AB[cv * 2048 + col] = a;
            AB[cv * 2048 + 1024 + col] = bt[col] - mean * a;
        }
        return;
    }
    __shared__ float rlds[1024];
#pragma unroll
    for (int r = 0; r < 4; ++r) rlds[tid + 256 * r] = root[tid + 256 * r];
    __syncthreads();
    const int o = tid & 31;
    const int gg = tid >> 5;
    const int n = blockIdx.x * 8 + gg;
    if (n >= NN) return;
    const int half = tid & 32;
    float xs = x[n * 32 + o];
    float acc = bias[o];
#pragma unroll
    for (int i = 0; i < 32; ++i) {
        float xi = __shfl(xs, half | i);
        acc = fmaf(xi, rlds[i * 32 + o], acc);
    }
    out[n * 32 + o] = acc;
}

// ------------- NNConv: wave-per-(edge,half), 8 cols/lane, weights in PINNED
// scalar VGPRs. lane's col j = lane + 64*(8*half+kk):
// i = parity + 16*half + 2*kk, o = lane&31, parity = lane>>5
#define CDECL(K) float w##K##0, w##K##1, w##K##2, w##K##3, w##K##4, w##K##5, bs##K, av##K, bv##K;
#define CLOAD(K) { const int _j = lane + (((half << 3) + K) << 6); \
    const float* _wr = nw + _j * 6; \
    w##K##0 = _wr[0]; w##K##1 = _wr[1]; w##K##2 = _wr[2]; \
    w##K##3 = _wr[3]; w##K##4 = _wr[4]; w##K##5 = _wr[5]; \
    bs##K = nb[_j]; av##K = A[_j]; bv##K = B[_j]; }
#define CPIN(K) asm("" : "+v"(w##K##0), "+v"(w##K##1), "+v"(w##K##2), "+v"(w##K##3), \
                         "+v"(w##K##4), "+v"(w##K##5), "+v"(bs##K), "+v"(av##K), "+v"(bv##K));
#define CACC(K, XK) { float _y = bs##K; \
    _y = fmaf(e0, w##K##0, _y); _y = fmaf(e1, w##K##1, _y); _y = fmaf(e2, w##K##2, _y); \
    _y = fmaf(e3, w##K##3, _y); _y = fmaf(e4, w##K##4, _y); _y = fmaf(e5, w##K##5, _y); \
    float _t = fmaf(av##K, fmaxf(_y, 0.f), bv##K); msg = fmaf(XK, _t, msg); }

__global__ __launch_bounds__(256, 4) void k_conv(const float* __restrict__ xin,
        const float* __restrict__ ea, const int* __restrict__ src, const int* __restrict__ dst,
        const float* __restrict__ nw, const float* __restrict__ nb,
        const float* __restrict__ A, const float* __restrict__ B,
        float* __restrict__ agg) {
    const int tid = threadIdx.x;
    const int lane = tid & 63;
    const int wid = tid >> 6;
    const int parity = lane >> 5;
    const int o = lane & 31;
    const int half = wid & 1;
    const int estream = (blockIdx.x << 1) | (wid >> 1);
    const int stride = gridDim.x << 1;

    CDECL(0) CDECL(1) CDECL(2) CDECL(3) CDECL(4) CDECL(5) CDECL(6) CDECL(7)
    CLOAD(0) CLOAD(1) CLOAD(2) CLOAD(3) CLOAD(4) CLOAD(5) CLOAD(6) CLOAD(7)
    CPIN(0) CPIN(1) CPIN(2) CPIN(3) CPIN(4) CPIN(5) CPIN(6) CPIN(7)

    int e = estream;
    int sc = 0, dc = 0;
    float e0 = 0, e1 = 0, e2 = 0, e3 = 0, e4 = 0, e5 = 0;
    if (e < NE) {
        sc = src[e]; dc = dst[e];
        const float* er = ea + e * 6;
        float2 a0 = *reinterpret_cast<const float2*>(er);
        float2 a1 = *reinterpret_cast<const float2*>(er + 2);
        float2 a2 = *reinterpret_cast<const float2*>(er + 4);
        e0 = a0.x; e1 = a0.y; e2 = a1.x; e3 = a1.y; e4 = a2.x; e5 = a2.y;
    }
    while (e < NE) {
        const int en = e + stride;
        int sn = 0, dn = 0;
        float n0 = 0, n1 = 0, n2 = 0, n3 = 0, n4 = 0, n5 = 0;
        if (en < NE) {
            sn = src[en]; dn = dst[en];
            const float* er = ea + en * 6;
            float2 a0 = *reinterpret_cast<const float2*>(er);
            float2 a1 = *reinterpret_cast<const float2*>(er + 2);
            float2 a2 = *reinterpret_cast<const float2*>(er + 4);
            n0 = a0.x; n1 = a0.y; n2 = a1.x; n3 = a1.y; n4 = a2.x; n5 = a2.y;
        }
        const float* xr = xin + sc * 32 + (half << 4);
        float4 q0 = *reinterpret_cast<const float4*>(xr);
        float4 q1 = *reinterpret_cast<const float4*>(xr + 4);
        float4 q2 = *reinterpret_cast<const float4*>(xr + 8);
        float4 q3 = *reinterpret_cast<const float4*>(xr + 12);
        float x0 = parity ? q0.y : q0.x, x1 = parity ? q0.w : q0.z;
        float x2 = parity ? q1.y : q1.x, x3 = parity ? q1.w : q1.z;
        float x4 = parity ? q2.y : q2.x, x5 = parity ? q2.w : q2.z;
        float x6 = parity ? q3.y : q3.x, x7 = parity ? q3.w : q3.z;
        float msg = 0.f;
        CACC(0, x0) CACC(1, x1) CACC(2, x2) CACC(3, x3)
        CACC(4, x4) CACC(5, x5) CACC(6, x6) CACC(7, x7)
        msg += __shfl_xor(msg, 32, 64);
        if (parity == 0) atomicAdd(&agg[dc * 32 + o], msg);
        sc = sn; dc = dn;
        e0 = n0; e1 = n1; e2 = n2; e3 = n3; e4 = n4; e5 = n5;
        e = en;
    }
}

// ---------------------------------------- lin1: relu(cat(x1,x2)@W^T+b) + stats
__global__ __launch_bounds__(384) void k_lin1a(const float* __restrict__ x1,
        const float* __restrict__ x2, const float* __restrict__ lw, const float* __restrict__ lb,
        float* __restrict__ pre, float* __restrict__ gsum, float* __restrict__ gsumsq) {
    __shared__ float cat[4][64];
    __shared__ float sh_s[96], sh_ss[96];
    const int tid = threadIdx.x;
    const int np = tid / 96;   // 0..3
    const int q = tid - np * 96;
    float w[64];
#pragma unroll
    for (int k = 0; k < 64; ++k) w[k] = lw[q * 64 + k];
    const float bq = lb[q];
    float s = 0.f, ss = 0.f;
    for (int nb = blockIdx.x * 4; nb < NN; nb += gridDim.x * 4) {
        __syncthreads();
        if (tid < 256) {
            int n2 = tid >> 6, k = tid & 63;
            cat[n2][k] = (k < 32) ? x1[(nb + n2) * 32 + k] : x2[(nb + n2) * 32 + (k - 32)];
        }
        __syncthreads();
        float v = bq;
#pragma unroll
        for (int k = 0; k < 64; ++k) v = fmaf(cat[np][k], w[k], v);
        float r = fmaxf(v, 0.f);
        pre[(nb + np) * 96 + q] = r;
        s += r; ss = fmaf(r, r, ss);
    }
    __syncthreads();
    if (tid < 96) { sh_s[tid] = 0.f; sh_ss[tid] = 0.f; }
    __syncthreads();
    atomicAdd(&sh_s[q], s);
    atomicAdd(&sh_ss[q], ss);
    __syncthreads();
    if (tid < 96) {
        atomicAdd(&gsum[tid], sh_s[tid]);
        atomicAdd(&gsumsq[tid], sh_ss[tid]);
    }
}

__global__ __launch_bounds__(384) void k_lin1b(const float* __restrict__ gsum,
        const float* __restrict__ gsumsq, const float* __restrict__ g, const float* __restrict__ beta,
        const float* __restrict__ pre, float* __restrict__ xc) {
    const int tid = threadIdx.x;
    const int np = tid / 96;
    const int q = tid - np * 96;
    const float invN = 1.f / NN;
    float mean = gsum[q] * invN;
    float var = fmaxf(gsumsq[q] * invN - mean * mean, 0.f);
    float a = g[q] * rsqrtf(var + EPS);
    float b = beta[q] - mean * a;
    for (int nb = blockIdx.x * 4; nb < NN; nb += gridDim.x * 4) {
        int n = nb + np;
        xc[n * 96 + q] = fmaf(a, pre[n * 96 + q], b);
    }
}

// ------------------------------------------------- Set2Set: whole loop per graph
__global__ __launch_bounds__(512) void k_s2s(const float* __restrict__ xc,
        const int* __restrict__ batch,
        const float* __restrict__ w_ih, const float* __restrict__ w_hh,
        const float* __restrict__ b_ih, const float* __restrict__ b_hh,
        float* __restrict__ qs_g, float* __restrict__ e_ws) {
    __shared__ float qs[192], h[96], c[96], gates[384];
    __shared__ float redm[8], reds[8];
    __shared__ float racc_s[5][96];
    __shared__ float sh_scal[2];   // [0]=emax, [1]=1/asum
    __shared__ int sse[2];
    const int tid = threadIdx.x;
    const int wid = tid >> 6, lane = tid & 63;
    const int b = blockIdx.x;
    if (tid < 2) {   // inline graph-range binary search (start of graph b+tid)
        int key = b + tid, lo = 0, hi = NN;
        while (lo < hi) { int mid = (lo + hi) >> 1; if (batch[mid] < key) lo = mid + 1; else hi = mid; }
        sse[tid] = lo;
    }
    if (tid < 192) qs[tid] = 0.f;
    if (tid < 96) { h[tid] = 0.f; c[tid] = 0.f; }
    __syncthreads();
    const int s = sse[0], t = sse[1];
    for (int step = 0; step < 3; ++step) {
        if (tid < 384) {
            float acc = b_ih[tid] + b_hh[tid];
            const float* wi = &w_ih[tid * 192];
#pragma unroll 8
            for (int k = 0; k < 192; ++k) acc = fmaf(qs[k], wi[k], acc);
            const float* wh = &w_hh[tid * 96];
#pragma unroll 8
            for (int k = 0; k < 96; ++k) acc = fmaf(h[k], wh[k], acc);
            gates[tid] = acc;
        }
        __syncthreads();
        if (tid < 96) {
            float ig = 1.f / (1.f + __expf(-gates[tid]));
            float fg = 1.f / (1.f + __expf(-gates[96 + tid]));
            float gg = tanhf(gates[192 + tid]);
            float og = 1.f / (1.f + __expf(-gates[288 + tid]));
            float cn = fg * c[tid] + ig * gg;
            c[tid] = cn;
            h[tid] = og * tanhf(cn);
        }
        __syncthreads();
        float pmax = -INFINITY;
        for (int n = s + tid; n < t; n += 512) {
            const float* xr = &xc[n * 96];
            float acc = 0.f;
#pragma unroll 8
            for (int k = 0; k < 96; ++k) acc = fmaf(xr[k], h[k], acc);
            e_ws[n] = acc;
            pmax = fmaxf(pmax, acc);
        }
#pragma unroll
        for (int off = 32; off > 0; off >>= 1) pmax = fmaxf(pmax, __shfl_down(pmax, off));
        if (lane == 0) redm[wid] = pmax;
        __syncthreads();
        if (tid == 0) {
            float m = redm[0];
#pragma unroll
            for (int i = 1; i < 8; ++i) m = fmaxf(m, redm[i]);
            if (!isfinite(m)) m = 0.f;
            sh_scal[0] = m;
        }
        __syncthreads();
        const float emax = sh_scal[0];
        float pa = 0.f;
        for (int n = s + tid; n < t; n += 512) {
            float a = __expf(e_ws[n] - emax);
            e_ws[n] = a;
            pa += a;
        }
#pragma unroll
        for (int off = 32; off > 0; off >>= 1) pa += __shfl_down(pa, off);
        if (lane == 0) reds[wid] = pa;
        __syncthreads();
        if (tid == 0) {
            float a2 = 0.f;
#pragma unroll
            for (int i = 0; i < 8; ++i) a2 += reds[i];
            sh_scal[1] = (a2 > 0.f) ? 1.f / a2 : 0.f;
        }
        __syncthreads();
        const int g = tid / 96, q = tid - g * 96;
        if (tid < 480) {
            float racc = 0.f;
            for (int n = s + g; n < t; n += 5)
                racc = fmaf(e_ws[n], xc[n * 96 + q], racc);
            racc_s[g][q] = racc;
        }
        __syncthreads();
        if (tid < 96) {
            float r = (racc_s[0][tid] + racc_s[1][tid] + racc_s[2][tid]
                     + racc_s[3][tid] + racc_s[4][tid]) * sh_scal[1];
            qs[tid] = h[tid];
            qs[96 + tid] = r;
        }
        __syncthreads();
    }
    if (tid < 192) qs_g[b * 192 + tid] = qs[tid];
}

// -------------------------------- xg = qs@s2s_w^T+b ; pre_m1 = relu(xg@m1^T+b)
__global__ __launch_bounds__(128) void k_xg(const float* __restrict__ qs_g,
        const float* __restrict__ sw, const float* __restrict__ sb,
        const float* __restrict__ m1w, const float* __restrict__ m1b,
        float* __restrict__ pre, float* __restrict__ gsum, float* __restrict__ gsumsq) {
    __shared__ float xg0[96];
    const int tid = threadIdx.x;
    const int b = blockIdx.x;
    if (tid < 96) {
        const float* q = &qs_g[b * 192];
        float acc = sb[tid];
        const float* w = &sw[tid * 192];
#pragma unroll 8
        for (int k = 0; k < 192; ++k) acc = fmaf(q[k], w[k], acc);
        xg0[tid] = acc;
    }
    __syncthreads();
    if (tid < 96) {
        float acc = m1b[tid];
        const float* w = &m1w[tid * 96];
#pragma unroll 8
        for (int k = 0; k < 96; ++k) acc = fmaf(xg0[k], w[k], acc);
        float r = fmaxf(acc, 0.f);
        pre[b * 96 + tid] = r;
        atomicAdd(&gsum[tid], r);
        atomicAdd(&gsumsq[tid], r * r);
    }
}

// ----------------------------------------- tail: BN(m1) -> m2 linear+relu+BN
__global__ __launch_bounds__(256) void k_tail(const float* __restrict__ pre,
        const float* __restrict__ gsum, const float* __restrict__ gsumsq,
        const float* __restrict__ g1, const float* __restrict__ beta1,
        const float* __restrict__ m2w, const float* __restrict__ m2b,
        const float* __restrict__ g2, const float* __restrict__ beta2,
        float* __restrict__ out) {
    __shared__ float xg1[100][97];
    __shared__ float pre2[200];
    __shared__ float ab2[4];
    const int tid = threadIdx.x;
    if (tid < 96) {
        const float invN = 1.f / NG;
        float mean = gsum[tid] * invN;
        float var = fmaxf(gsumsq[tid] * invN - mean * mean, 0.f);
        float a = g1[tid] * rsqrtf(var + EPS);
        float bb = beta1[tid] - mean * a;
        for (int n = 0; n < NG; ++n)
            xg1[n][tid] = fmaf(a, pre[n * 96 + tid], bb);
    }
    __syncthreads();
    if (tid < 200) {
        int n = tid >> 1, cc = tid & 1;
        float acc = m2b[cc];
        const float* w = &m2w[cc * 96];
#pragma unroll 8
        for (int k = 0; k < 96; ++k) acc = fmaf(xg1[n][k], w[k], acc);
        pre2[tid] = fmaxf(acc, 0.f);
    }
    __syncthreads();
    if (tid < 2) {
        float s = 0.f, ss = 0.f;
        for (int n = 0; n < NG; ++n) { float v = pre2[n * 2 + tid]; s += v; ss = fmaf(v, v, ss); }
        const float invN = 1.f / NG;
        float mean = s * invN;
        float var = fmaxf(ss * invN - mean * mean, 0.f);
        float a = g2[tid] * rsqrtf(var + EPS);
        ab2[tid] = a;
        ab2[2 + tid] = beta2[tid] - mean * a;
    }
    __syncthreads();
    if (tid < 200) {
        int cc = tid & 1;
        out[tid] = fmaf(ab2[cc], pre2[tid], ab2[2 + cc]);
    }
}

extern "C" void kernel_launch(void* const* d_in, const int* in_sizes, int n_in,
                              void* d_out, int out_size, void* d_ws, size_t ws_size,
                              hipStream_t stream) {
    (void)in_sizes; (void)n_in; (void)out_size; (void)ws_size;
    const float* x       = (const float*)d_in[0];
    const float* ea      = (const float*)d_in[1];
    const float* c1w     = (const float*)d_in[2];
    const float* c1b     = (const float*)d_in[3];
    const float* c1g     = (const float*)d_in[4];
    const float* c1beta  = (const float*)d_in[5];
    const float* c1root  = (const float*)d_in[6];
    const float* c1bias  = (const float*)d_in[7];
    const float* c2w     = (const float*)d_in[8];
    const float* c2b     = (const float*)d_in[9];
    const float* c2g     = (const float*)d_in[10];
    const float* c2beta  = (const float*)d_in[11];
    const float* c2root  = (const float*)d_in[12];
    const float* c2bias  = (const float*)d_in[13];
    const float* lin1w   = (const float*)d_in[14];
    const float* lin1b   = (const float*)d_in[15];
    const float* lin1g   = (const float*)d_in[16];
    const float* lin1bt  = (const float*)d_in[17];
    const float* wih     = (const float*)d_in[18];
    const float* whh     = (const float*)d_in[19];
    const float* bih     = (const float*)d_in[20];
    const float* bhh     = (const float*)d_in[21];
    const float* s2sw    = (const float*)d_in[22];
    const float* s2sb    = (const float*)d_in[23];
    const float* m1w     = (const float*)d_in[24];
    const float* m1b     = (const float*)d_in[25];
    const float* m1g     = (const float*)d_in[26];
    const float* m1beta  = (const float*)d_in[27];
    const float* m2w     = (const float*)d_in[28];
    const float* m2b     = (const float*)d_in[29];
    const float* m2g     = (const float*)d_in[30];
    const float* m2beta  = (const float*)d_in[31];
    const int* src       = (const int*)d_in[32];
    const int* dst       = (const int*)d_in[33];
    const int* batch     = (const int*)d_in[34];

    float* ws = (float*)d_ws;
    float* stats  = ws;                 // 4096
    float* AB     = ws + 4096;          // 4096: A1|B1|A2|B2
    float* linst  = ws + 8192;          // 192
    float* m1st   = ws + 8384;          // 192
    float* x1     = ws + 8704;          // 320000
    float* x2     = x1 + 320000;        // 320000
    float* prelin = x2 + 320000;        // 960000 (BN in-place -> xc)
    float* e_ws   = prelin + 960000;    // 10000
    float* qs_g   = e_ws + 10000;       // 19200
    float* prem1  = qs_g + 19200;       // 9600

    hipMemsetAsync(ws, 0, 8576 * sizeof(float), stream);

    // ---- fused BN stats for both convs
    k_stats2<<<625, 512, 0, stream>>>(ea, c1w, c1b, c2w, c2b, stats);

    // ---- conv1 (root1 also computes both convs' BN affines in its last block)
    k_root<<<1251, 256, 0, stream>>>(x, c1root, c1bias, x1,
                                     1, stats, c1g, c1beta, c2g, c2beta, AB);
    k_conv<<<1024, 256, 0, stream>>>(x, ea, src, dst, c1w, c1b, AB, AB + 1024, x1);

    // ---- conv2
    k_root<<<1250, 256, 0, stream>>>(x1, c2root, c2bias, x2,
                                     0, stats, c1g, c1beta, c2g, c2beta, AB);
    k_conv<<<1024, 256, 0, stream>>>(x1, ea, src, dst, c2w, c2b, AB + 2048, AB + 3072, x2);

    // ---- lin1 (Linear+ReLU+BN)
    k_lin1a<<<500, 384, 0, stream>>>(x1, x2, lin1w, lin1b, prelin, linst, linst + 96);
    k_lin1b<<<500, 384, 0, stream>>>(linst, linst + 96, lin1g, lin1bt, prelin, prelin);

    // ---- Set2Set (graph ranges found in-kernel)
    k_s2s<<<100, 512, 0, stream>>>(prelin, batch, wih, whh, bih, bhh, qs_g, e_ws);

    // ---- tail MLPs
    k_xg<<<100, 128, 0, stream>>>(qs_g, s2sw, s2sb, m1w, m1b, prem1, m1st, m1st + 96);
    k_tail<<<1, 256, 0, stream>>>(prem1, m1st, m1st + 96, m1g, m1beta,
                                  m2w, m2b, m2g, m2beta, (float*)d_out);
}

// Round 8
// 391.442 us; speedup vs baseline: 1.0372x; 1.0372x over previous
//
#include <hip/hip_runtime.h>
#include <math.h>

#define NN 10000       // N_NODES
#define NE 160000      // N_EDGES
#define NG 100         // N_GRAPHS
#define DD 32
#define QQ 96
#define EPS 1e-5f

// ---------------- fused BN stats for BOTH convs' edge-MLPs, 1 col/thread.
// Per-thread live state: 7 weights + 2 acc + temps ~ 16 VGPR (below the
// allocator's observed ~24 spill threshold; R3-R7 showed >24 invariants
// always spill to scratch). ea via block-uniform s_loads (SGPR fma operand).
// grid: 2500 = 625 edge-chunks x 4 col-groups of 512.
// stats layout: [0..1023] c1 sum | [1024..2047] c1 sumsq | [2048..3071] c2 sum | [3072..4095] c2 sumsq
__global__ __launch_bounds__(512) void k_stats3(const float* __restrict__ ea,
        const float* __restrict__ w1, const float* __restrict__ b1,
        const float* __restrict__ w2, const float* __restrict__ b2,
        float* __restrict__ stats) {
    const int tid = threadIdx.x;
    const int grp = blockIdx.x & 3;
    const int chunk = blockIdx.x >> 2;
    const int conv = grp >> 1;                    // block-uniform
    const int col = ((grp & 1) << 9) | tid;       // 0..1023
    const float* w = conv ? w2 : w1;
    const float* bbp = conv ? b2 : b1;
    const float* wr = w + col * 6;
    float w0 = wr[0], w1v = wr[1], w2v = wr[2], w3v = wr[3], w4v = wr[4], w5v = wr[5];
    float bs = bbp[col];
    asm("" : "+v"(w0), "+v"(w1v), "+v"(w2v), "+v"(w3v), "+v"(w4v), "+v"(w5v), "+v"(bs));
    float s = 0.f, ss = 0.f;
    const int base = chunk * 256;
#pragma unroll 4
    for (int el = 0; el < 256; ++el) {
        const float* er = ea + (base + el) * 6;   // block-uniform -> s_load
        float e0 = er[0], e1 = er[1], e2 = er[2], e3 = er[3], e4 = er[4], e5 = er[5];
        float y = bs;
        y = fmaf(e0, w0, y); y = fmaf(e1, w1v, y); y = fmaf(e2, w2v, y);
        y = fmaf(e3, w3v, y); y = fmaf(e4, w4v, y); y = fmaf(e5, w5v, y);
        float r = fmaxf(y, 0.f);
        s += r; ss = fmaf(r, r, ss);
    }
    atomicAdd(&stats[conv * 2048 + col], s);
    atomicAdd(&stats[conv * 2048 + 1024 + col], ss);
}

// -------- k_root: out[n,o] = bias[o] + x[n]@root.  Block gridDim-1 (optional,
// when doFin!=0) instead computes BOTH convs' BN affines from stats.
// AB layout: [0..1023] A1 | [1024..2047] B1 | [2048..3071] A2 | [3072..4095] B2
__global__ __launch_bounds__(256) void k_root(const float* __restrict__ x,
        const float* __restrict__ root, const float* __restrict__ bias,
        float* __restrict__ out,
        int doFin, const float* __restrict__ stats,
        const float* __restrict__ g1, const float* __restrict__ beta1,
        const float* __restrict__ g2, const float* __restrict__ beta2,
        float* __restrict__ AB) {
    const int tid = threadIdx.x;
    if (doFin && blockIdx.x == gridDim.x - 1) {
        const float invE = 1.f / NE;
        for (int j = tid; j < 2048; j += 256) {
            int cv = j >> 10, col = j & 1023;
            const float* st = stats + cv * 2048;
            const float* g = cv ? g2 : g1;
            const float* bt = cv ? beta2 : beta1;
            float mean = st[col] * invE;
            float var = fmaxf(st[1024 + col] * invE - mean * mean, 0.f);
            float a = g[col] * rsqrtf(var + EPS);
            AB[cv * 2048 + col] = a;
            AB[cv * 2048 + 1024 + col] = bt[col] - mean * a;
        }
        return;
    }
    __shared__ float rlds[1024];
#pragma unroll
    for (int r = 0; r < 4; ++r) rlds[tid + 256 * r] = root[tid + 256 * r];
    __syncthreads();
    const int o = tid & 31;
    const int gg = tid >> 5;
    const int n = blockIdx.x * 8 + gg;
    if (n >= NN) return;
    const int half = tid & 32;
    float xs = x[n * 32 + o];
    float acc = bias[o];
#pragma unroll
    for (int i = 0; i < 32; ++i) {
        float xi = __shfl(xs, half | i);
        acc = fmaf(xi, rlds[i * 32 + o], acc);
    }
    out[n * 32 + o] = acc;
}

// ------------- NNConv: edge-per-block, 4 waves = 4 i-quarters, 4 cols/lane.
// lane's col j(kk) = (q*8 + 2*kk + p)*32 + o; q=wave 0..3, p=lane>>5, o=lane&31.
// src/dst/ea are block-uniform -> s_loads. 36 weight invariants/lane, pinned,
// LB(256,2) caps VGPR at ~256 so the allocator has room.
#define CDECL(K) float w##K##0, w##K##1, w##K##2, w##K##3, w##K##4, w##K##5, bs##K, av##K, bv##K;
#define CLOAD(K) { const int _j = (((q << 3) + (K << 1) + p) << 5) | o; \
    const float* _wr = nw + _j * 6; \
    w##K##0 = _wr[0]; w##K##1 = _wr[1]; w##K##2 = _wr[2]; \
    w##K##3 = _wr[3]; w##K##4 = _wr[4]; w##K##5 = _wr[5]; \
    bs##K = nb[_j]; av##K = A[_j]; bv##K = B[_j]; }
#define CPIN(K) asm("" : "+v"(w##K##0), "+v"(w##K##1), "+v"(w##K##2), "+v"(w##K##3), \
                         "+v"(w##K##4), "+v"(w##K##5), "+v"(bs##K), "+v"(av##K), "+v"(bv##K));
#define CACC(K, XK) { float _y = bs##K; \
    _y = fmaf(e0, w##K##0, _y); _y = fmaf(e1, w##K##1, _y); _y = fmaf(e2, w##K##2, _y); \
    _y = fmaf(e3, w##K##3, _y); _y = fmaf(e4, w##K##4, _y); _y = fmaf(e5, w##K##5, _y); \
    float _t = fmaf(av##K, fmaxf(_y, 0.f), bv##K); msg = fmaf(XK, _t, msg); }

__global__ __launch_bounds__(256, 2) void k_conv(const float* __restrict__ xin,
        const float* __restrict__ ea, const int* __restrict__ src, const int* __restrict__ dst,
        const float* __restrict__ nw, const float* __restrict__ nb,
        const float* __restrict__ A, const float* __restrict__ B,
        float* __restrict__ agg) {
    const int tid = threadIdx.x;
    const int lane = tid & 63;
    const int q = tid >> 6;        // wave = i-quarter
    const int p = lane >> 5;
    const int o = lane & 31;

    CDECL(0) CDECL(1) CDECL(2) CDECL(3)
    CLOAD(0) CLOAD(1) CLOAD(2) CLOAD(3)
    CPIN(0) CPIN(1) CPIN(2) CPIN(3)

    for (int e = blockIdx.x; e < NE; e += gridDim.x) {
        const int sc = src[e];                 // block-uniform -> s_load
        const int dc = dst[e];
        const float* er = ea + e * 6;          // block-uniform -> s_load
        float e0 = er[0], e1 = er[1], e2 = er[2], e3 = er[3], e4 = er[4], e5 = er[5];
        const float* xr = xin + sc * 32 + (q << 3) + p;
        float x0 = xr[0], x1 = xr[2], x2 = xr[4], x3 = xr[6];
        float msg = 0.f;
        CACC(0, x0) CACC(1, x1) CACC(2, x2) CACC(3, x3)
        msg += __shfl_xor(msg, 32, 64);
        if (p == 0) atomicAdd(&agg[dc * 32 + o], msg);
    }
}

// ---------------------------------------- lin1: relu(cat(x1,x2)@W^T+b) + stats
__global__ __launch_bounds__(384) void k_lin1a(const float* __restrict__ x1,
        const float* __restrict__ x2, const float* __restrict__ lw, const float* __restrict__ lb,
        float* __restrict__ pre, float* __restrict__ gsum, float* __restrict__ gsumsq) {
    __shared__ float cat[4][64];
    __shared__ float sh_s[96], sh_ss[96];
    const int tid = threadIdx.x;
    const int np = tid / 96;   // 0..3
    const int q = tid - np * 96;
    float w[64];
#pragma unroll
    for (int k = 0; k < 64; ++k) w[k] = lw[q * 64 + k];
    const float bq = lb[q];
    float s = 0.f, ss = 0.f;
    for (int nb = blockIdx.x * 4; nb < NN; nb += gridDim.x * 4) {
        __syncthreads();
        if (tid < 256) {
            int n2 = tid >> 6, k = tid & 63;
            cat[n2][k] = (k < 32) ? x1[(nb + n2) * 32 + k] : x2[(nb + n2) * 32 + (k - 32)];
        }
        __syncthreads();
        float v = bq;
#pragma unroll
        for (int k = 0; k < 64; ++k) v = fmaf(cat[np][k], w[k], v);
        float r = fmaxf(v, 0.f);
        pre[(nb + np) * 96 + q] = r;
        s += r; ss = fmaf(r, r, ss);
    }
    __syncthreads();
    if (tid < 96) { sh_s[tid] = 0.f; sh_ss[tid] = 0.f; }
    __syncthreads();
    atomicAdd(&sh_s[q], s);
    atomicAdd(&sh_ss[q], ss);
    __syncthreads();
    if (tid < 96) {
        atomicAdd(&gsum[tid], sh_s[tid]);
        atomicAdd(&gsumsq[tid], sh_ss[tid]);
    }
}

__global__ __launch_bounds__(384) void k_lin1b(const float* __restrict__ gsum,
        const float* __restrict__ gsumsq, const float* __restrict__ g, const float* __restrict__ beta,
        const float* __restrict__ pre, float* __restrict__ xc) {
    const int tid = threadIdx.x;
    const int np = tid / 96;
    const int q = tid - np * 96;
    const float invN = 1.f / NN;
    float mean = gsum[q] * invN;
    float var = fmaxf(gsumsq[q] * invN - mean * mean, 0.f);
    float a = g[q] * rsqrtf(var + EPS);
    float b = beta[q] - mean * a;
    for (int nb = blockIdx.x * 4; nb < NN; nb += gridDim.x * 4) {
        int n = nb + np;
        xc[n * 96 + q] = fmaf(a, pre[n * 96 + q], b);
    }
}

// ------------------------------------------------- Set2Set: whole loop per graph
__global__ __launch_bounds__(512) void k_s2s(const float* __restrict__ xc,
        const int* __restrict__ batch,
        const float* __restrict__ w_ih, const float* __restrict__ w_hh,
        const float* __restrict__ b_ih, const float* __restrict__ b_hh,
        float* __restrict__ qs_g, float* __restrict__ e_ws) {
    __shared__ float qs[192], h[96], c[96], gates[384];
    __shared__ float redm[8], reds[8];
    __shared__ float racc_s[5][96];
    __shared__ float sh_scal[2];   // [0]=emax, [1]=1/asum
    __shared__ int sse[2];
    const int tid = threadIdx.x;
    const int wid = tid >> 6, lane = tid & 63;
    const int b = blockIdx.x;
    if (tid < 2) {   // inline graph-range binary search (start of graph b+tid)
        int key = b + tid, lo = 0, hi = NN;
        while (lo < hi) { int mid = (lo + hi) >> 1; if (batch[mid] < key) lo = mid + 1; else hi = mid; }
        sse[tid] = lo;
    }
    if (tid < 192) qs[tid] = 0.f;
    if (tid < 96) { h[tid] = 0.f; c[tid] = 0.f; }
    __syncthreads();
    const int s = sse[0], t = sse[1];
    for (int step = 0; step < 3; ++step) {
        if (tid < 384) {
            float acc = b_ih[tid] + b_hh[tid];
            const float* wi = &w_ih[tid * 192];
#pragma unroll 8
            for (int k = 0; k < 192; ++k) acc = fmaf(qs[k], wi[k], acc);
            const float* wh = &w_hh[tid * 96];
#pragma unroll 8
            for (int k = 0; k < 96; ++k) acc = fmaf(h[k], wh[k], acc);
            gates[tid] = acc;
        }
        __syncthreads();
        if (tid < 96) {
            float ig = 1.f / (1.f + __expf(-gates[tid]));
            float fg = 1.f / (1.f + __expf(-gates[96 + tid]));
            float gg = tanhf(gates[192 + tid]);
            float og = 1.f / (1.f + __expf(-gates[288 + tid]));
            float cn = fg * c[tid] + ig * gg;
            c[tid] = cn;
            h[tid] = og * tanhf(cn);
        }
        __syncthreads();
        float pmax = -INFINITY;
        for (int n = s + tid; n < t; n += 512) {
            const float* xr = &xc[n * 96];
            float acc = 0.f;
#pragma unroll 8
            for (int k = 0; k < 96; ++k) acc = fmaf(xr[k], h[k], acc);
            e_ws[n] = acc;
            pmax = fmaxf(pmax, acc);
        }
#pragma unroll
        for (int off = 32; off > 0; off >>= 1) pmax = fmaxf(pmax, __shfl_down(pmax, off));
        if (lane == 0) redm[wid] = pmax;
        __syncthreads();
        if (tid == 0) {
            float m = redm[0];
#pragma unroll
            for (int i = 1; i < 8; ++i) m = fmaxf(m, redm[i]);
            if (!isfinite(m)) m = 0.f;
            sh_scal[0] = m;
        }
        __syncthreads();
        const float emax = sh_scal[0];
        float pa = 0.f;
        for (int n = s + tid; n < t; n += 512) {
            float a = __expf(e_ws[n] - emax);
            e_ws[n] = a;
            pa += a;
        }
#pragma unroll
        for (int off = 32; off > 0; off >>= 1) pa += __shfl_down(pa, off);
        if (lane == 0) reds[wid] = pa;
        __syncthreads();
        if (tid == 0) {
            float a2 = 0.f;
#pragma unroll
            for (int i = 0; i < 8; ++i) a2 += reds[i];
            sh_scal[1] = (a2 > 0.f) ? 1.f / a2 : 0.f;
        }
        __syncthreads();
        const int g = tid / 96, q = tid - g * 96;
        if (tid < 480) {
            float racc = 0.f;
            for (int n = s + g; n < t; n += 5)
                racc = fmaf(e_ws[n], xc[n * 96 + q], racc);
            racc_s[g][q] = racc;
        }
        __syncthreads();
        if (tid < 96) {
            float r = (racc_s[0][tid] + racc_s[1][tid] + racc_s[2][tid]
                     + racc_s[3][tid] + racc_s[4][tid]) * sh_scal[1];
            qs[tid] = h[tid];
            qs[96 + tid] = r;
        }
        __syncthreads();
    }
    if (tid < 192) qs_g[b * 192 + tid] = qs[tid];
}

// -------------------------------- xg = qs@s2s_w^T+b ; pre_m1 = relu(xg@m1^T+b)
__global__ __launch_bounds__(128) void k_xg(const float* __restrict__ qs_g,
        const float* __restrict__ sw, const float* __restrict__ sb,
        const float* __restrict__ m1w, const float* __restrict__ m1b,
        float* __restrict__ pre, float* __restrict__ gsum, float* __restrict__ gsumsq) {
    __shared__ float xg0[96];
    const int tid = threadIdx.x;
    const int b = blockIdx.x;
    if (tid < 96) {
        const float* q = &qs_g[b * 192];
        float acc = sb[tid];
        const float* w = &sw[tid * 192];
#pragma unroll 8
        for (int k = 0; k < 192; ++k) acc = fmaf(q[k], w[k], acc);
        xg0[tid] = acc;
    }
    __syncthreads();
    if (tid < 96) {
        float acc = m1b[tid];
        const float* w = &m1w[tid * 96];
#pragma unroll 8
        for (int k = 0; k < 96; ++k) acc = fmaf(xg0[k], w[k], acc);
        float r = fmaxf(acc, 0.f);
        pre[b * 96 + tid] = r;
        atomicAdd(&gsum[tid], r);
        atomicAdd(&gsumsq[tid], r * r);
    }
}

// ----------------------------------------- tail: BN(m1) -> m2 linear+relu+BN
__global__ __launch_bounds__(256) void k_tail(const float* __restrict__ pre,
        const float* __restrict__ gsum, const float* __restrict__ gsumsq,
        const float* __restrict__ g1, const float* __restrict__ beta1,
        const float* __restrict__ m2w, const float* __restrict__ m2b,
        const float* __restrict__ g2, const float* __restrict__ beta2,
        float* __restrict__ out) {
    __shared__ float xg1[100][97];
    __shared__ float pre2[200];
    __shared__ float ab2[4];
    const int tid = threadIdx.x;
    if (tid < 96) {
        const float invN = 1.f / NG;
        float mean = gsum[tid] * invN;
        float var = fmaxf(gsumsq[tid] * invN - mean * mean, 0.f);
        float a = g1[tid] * rsqrtf(var + EPS);
        float bb = beta1[tid] - mean * a;
        for (int n = 0; n < NG; ++n)
            xg1[n][tid] = fmaf(a, pre[n * 96 + tid], bb);
    }
    __syncthreads();
    if (tid < 200) {
        int n = tid >> 1, cc = tid & 1;
        float acc = m2b[cc];
        const float* w = &m2w[cc * 96];
#pragma unroll 8
        for (int k = 0; k < 96; ++k) acc = fmaf(xg1[n][k], w[k], acc);
        pre2[tid] = fmaxf(acc, 0.f);
    }
    __syncthreads();
    if (tid < 2) {
        float s = 0.f, ss = 0.f;
        for (int n = 0; n < NG; ++n) { float v = pre2[n * 2 + tid]; s += v; ss = fmaf(v, v, ss); }
        const float invN = 1.f / NG;
        float mean = s * invN;
        float var = fmaxf(ss * invN - mean * mean, 0.f);
        float a = g2[tid] * rsqrtf(var + EPS);
        ab2[tid] = a;
        ab2[2 + tid] = beta2[tid] - mean * a;
    }
    __syncthreads();
    if (tid < 200) {
        int cc = tid & 1;
        out[tid] = fmaf(ab2[cc], pre2[tid], ab2[2 + cc]);
    }
}

extern "C" void kernel_launch(void* const* d_in, const int* in_sizes, int n_in,
                              void* d_out, int out_size, void* d_ws, size_t ws_size,
                              hipStream_t stream) {
    (void)in_sizes; (void)n_in; (void)out_size; (void)ws_size;
    const float* x       = (const float*)d_in[0];
    const float* ea      = (const float*)d_in[1];
    const float* c1w     = (const float*)d_in[2];
    const float* c1b     = (const float*)d_in[3];
    const float* c1g     = (const float*)d_in[4];
    const float* c1beta  = (const float*)d_in[5];
    const float* c1root  = (const float*)d_in[6];
    const float* c1bias  = (const float*)d_in[7];
    const float* c2w     = (const float*)d_in[8];
    const float* c2b     = (const float*)d_in[9];
    const float* c2g     = (const float*)d_in[10];
    const float* c2beta  = (const float*)d_in[11];
    const float* c2root  = (const float*)d_in[12];
    const float* c2bias  = (const float*)d_in[13];
    const float* lin1w   = (const float*)d_in[14];
    const float* lin1b   = (const float*)d_in[15];
    const float* lin1g   = (const float*)d_in[16];
    const float* lin1bt  = (const float*)d_in[17];
    const float* wih     = (const float*)d_in[18];
    const float* whh     = (const float*)d_in[19];
    const float* bih     = (const float*)d_in[20];
    const float* bhh     = (const float*)d_in[21];
    const float* s2sw    = (const float*)d_in[22];
    const float* s2sb    = (const float*)d_in[23];
    const float* m1w     = (const float*)d_in[24];
    const float* m1b     = (const float*)d_in[25];
    const float* m1g     = (const float*)d_in[26];
    const float* m1beta  = (const float*)d_in[27];
    const float* m2w     = (const float*)d_in[28];
    const float* m2b     = (const float*)d_in[29];
    const float* m2g     = (const float*)d_in[30];
    const float* m2beta  = (const float*)d_in[31];
    const int* src       = (const int*)d_in[32];
    const int* dst       = (const int*)d_in[33];
    const int* batch     = (const int*)d_in[34];

    float* ws = (float*)d_ws;
    float* stats  = ws;                 // 4096
    float* AB     = ws + 4096;          // 4096: A1|B1|A2|B2
    float* linst  = ws + 8192;          // 192
    float* m1st   = ws + 8384;          // 192
    float* x1     = ws + 8704;          // 320000
    float* x2     = x1 + 320000;        // 320000
    float* prelin = x2 + 320000;        // 960000 (BN in-place -> xc)
    float* e_ws   = prelin + 960000;    // 10000
    float* qs_g   = e_ws + 10000;       // 19200
    float* prem1  = qs_g + 19200;       // 9600

    hipMemsetAsync(ws, 0, 8576 * sizeof(float), stream);

    // ---- fused BN stats for both convs (1 col/thread, low-VGPR)
    k_stats3<<<2500, 512, 0, stream>>>(ea, c1w, c1b, c2w, c2b, stats);

    // ---- conv1 (root1 also computes both convs' BN affines in its last block)
    k_root<<<1251, 256, 0, stream>>>(x, c1root, c1bias, x1,
                                     1, stats, c1g, c1beta, c2g, c2beta, AB);
    k_conv<<<2048, 256, 0, stream>>>(x, ea, src, dst, c1w, c1b, AB, AB + 1024, x1);

    // ---- conv2
    k_root<<<1250, 256, 0, stream>>>(x1, c2root, c2bias, x2,
                                     0, stats, c1g, c1beta, c2g, c2beta, AB);
    k_conv<<<2048, 256, 0, stream>>>(x1, ea, src, dst, c2w, c2b, AB + 2048, AB + 3072, x2);

    // ---- lin1 (Linear+ReLU+BN)
    k_lin1a<<<500, 384, 0, stream>>>(x1, x2, lin1w, lin1b, prelin, linst, linst + 96);
    k_lin1b<<<500, 384, 0, stream>>>(linst, linst + 96, lin1g, lin1bt, prelin, prelin);

    // ---- Set2Set (graph ranges found in-kernel)
    k_s2s<<<100, 512, 0, stream>>>(prelin, batch, wih, whh, bih, bhh, qs_g, e_ws);

    // ---- tail MLPs
    k_xg<<<100, 128, 0, stream>>>(qs_g, s2sw, s2sb, m1w, m1b, prem1, m1st, m1st + 96);
    k_tail<<<1, 256, 0, stream>>>(prem1, m1st, m1st + 96, m1g, m1beta,
                                  m2w, m2b, m2g, m2beta, (float*)d_out);
}

// Round 9
// 339.696 us; speedup vs baseline: 1.1952x; 1.1523x over previous
//
#include <hip/hip_runtime.h>
#include <math.h>

#define NN 10000       // N_NODES
#define NE 160000      // N_EDGES
#define NG 100         // N_GRAPHS
#define DD 32
#define QQ 96
#define EPS 1e-5f

// ---------------- fused BN stats for BOTH convs' edge-MLPs.
// One column per thread, conv1+conv2 paired as float2 lanes -> isomorphic fma
// pairs can fuse to v_pk_fma_f32 (packed 2xf32). 14 invariant floats/thread
// (R8 proved 7 safe; R6 showed 36 spills). ea staged in LDS once per block,
// read per-edge as wave-uniform broadcast float2 (conflict-free).
// grid: 1250 = 625 edge-chunks x 2 col-halves; 512 threads.
// stats layout: [0..1023] c1 sum | [1024..2047] c1 sumsq | [2048..3071] c2 sum | [3072..4095] c2 sumsq
__global__ __launch_bounds__(512) void k_stats4(const float* __restrict__ ea,
        const float* __restrict__ w1, const float* __restrict__ b1,
        const float* __restrict__ w2, const float* __restrict__ b2,
        float* __restrict__ stats) {
    __shared__ float eas[1536];   // 256 edges x 6 attrs
    const int tid = threadIdx.x;
    const int chunk = blockIdx.x >> 1;
    const int ct = ((blockIdx.x & 1) << 9) | tid;   // column 0..1023
    const float* wr1 = w1 + ct * 6;
    const float* wr2 = w2 + ct * 6;
    float2 W0 = make_float2(wr1[0], wr2[0]);
    float2 W1 = make_float2(wr1[1], wr2[1]);
    float2 W2 = make_float2(wr1[2], wr2[2]);
    float2 W3 = make_float2(wr1[3], wr2[3]);
    float2 W4 = make_float2(wr1[4], wr2[4]);
    float2 W5 = make_float2(wr1[5], wr2[5]);
    float2 Bb = make_float2(b1[ct], b2[ct]);
    float2 S = make_float2(0.f, 0.f), SS = make_float2(0.f, 0.f);
    const int base = chunk * 1536;
    eas[tid]        = ea[base + tid];
    eas[tid + 512]  = ea[base + tid + 512];
    eas[tid + 1024] = ea[base + tid + 1024];
    __syncthreads();
#pragma unroll 4
    for (int el = 0; el < 256; ++el) {
        const float* ep = &eas[el * 6];           // wave-uniform -> broadcast
        float2 p0 = *reinterpret_cast<const float2*>(ep);
        float2 p1 = *reinterpret_cast<const float2*>(ep + 2);
        float2 p2 = *reinterpret_cast<const float2*>(ep + 4);
        float2 y = Bb;
        y.x = fmaf(p0.x, W0.x, y.x); y.y = fmaf(p0.x, W0.y, y.y);
        y.x = fmaf(p0.y, W1.x, y.x); y.y = fmaf(p0.y, W1.y, y.y);
        y.x = fmaf(p1.x, W2.x, y.x); y.y = fmaf(p1.x, W2.y, y.y);
        y.x = fmaf(p1.y, W3.x, y.x); y.y = fmaf(p1.y, W3.y, y.y);
        y.x = fmaf(p2.x, W4.x, y.x); y.y = fmaf(p2.x, W4.y, y.y);
        y.x = fmaf(p2.y, W5.x, y.x); y.y = fmaf(p2.y, W5.y, y.y);
        float rx = fmaxf(y.x, 0.f), ry = fmaxf(y.y, 0.f);
        S.x += rx; S.y += ry;
        SS.x = fmaf(rx, rx, SS.x); SS.y = fmaf(ry, ry, SS.y);
    }
    atomicAdd(&stats[ct], S.x);
    atomicAdd(&stats[1024 + ct], SS.x);
    atomicAdd(&stats[2048 + ct], S.y);
    atomicAdd(&stats[3072 + ct], SS.y);
}

// -------- k_root: out[n,o] = bias[o] + x[n]@root.  Block gridDim-1 (optional,
// when doFin!=0) instead computes BOTH convs' BN affines from stats.
// AB layout: [0..1023] A1 | [1024..2047] B1 | [2048..3071] A2 | [3072..4095] B2
__global__ __launch_bounds__(256) void k_root(const float* __restrict__ x,
        const float* __restrict__ root, const float* __restrict__ bias,
        float* __restrict__ out,
        int doFin, const float* __restrict__ stats,
        const float* __restrict__ g1, const float* __restrict__ beta1,
        const float* __restrict__ g2, const float* __restrict__ beta2,
        float* __restrict__ AB) {
    const int tid = threadIdx.x;
    if (doFin && blockIdx.x == gridDim.x - 1) {
        const float invE = 1.f / NE;
        for (int j = tid; j < 2048; j += 256) {
            int cv = j >> 10, col = j & 1023;
            const float* st = stats + cv * 2048;
            const float* g = cv ? g2 : g1;
            const float* bt = cv ? beta2 : beta1;
            float mean = st[col] * invE;
            float var = fmaxf(st[1024 + col] * invE - mean * mean, 0.f);
            float a = g[col] * rsqrtf(var + EPS);
            AB[cv * 2048 + col] = a;
            AB[cv * 2048 + 1024 + col] = bt[col] - mean * a;
        }
        return;
    }
    __shared__ float rlds[1024];
#pragma unroll
    for (int r = 0; r < 4; ++r) rlds[tid + 256 * r] = root[tid + 256 * r];
    __syncthreads();
    const int o = tid & 31;
    const int gg = tid >> 5;
    const int n = blockIdx.x * 8 + gg;
    if (n >= NN) return;
    const int half = tid & 32;
    float xs = x[n * 32 + o];
    float acc = bias[o];
#pragma unroll
    for (int i = 0; i < 32; ++i) {
        float xi = __shfl(xs, half | i);
        acc = fmaf(xi, rlds[i * 32 + o], acc);
    }
    out[n * 32 + o] = acc;
}

// ------------- NNConv: edge-per-block-stream, 4 waves = 4 i-quarters, 4 cols/lane,
// next-edge scalar+x prefetch to hide s_load/VMEM latency under the FMA block.
// lane's col j(kk) = (q*8 + 2*kk + p)*32 + o; q=wave 0..3, p=lane>>5, o=lane&31.
#define CDECL(K) float w##K##0, w##K##1, w##K##2, w##K##3, w##K##4, w##K##5, bs##K, av##K, bv##K;
#define CLOAD(K) { const int _j = (((q << 3) + (K << 1) + p) << 5) | o; \
    const float* _wr = nw + _j * 6; \
    w##K##0 = _wr[0]; w##K##1 = _wr[1]; w##K##2 = _wr[2]; \
    w##K##3 = _wr[3]; w##K##4 = _wr[4]; w##K##5 = _wr[5]; \
    bs##K = nb[_j]; av##K = A[_j]; bv##K = B[_j]; }
#define CPIN(K) asm("" : "+v"(w##K##0), "+v"(w##K##1), "+v"(w##K##2), "+v"(w##K##3), \
                         "+v"(w##K##4), "+v"(w##K##5), "+v"(bs##K), "+v"(av##K), "+v"(bv##K));
#define CACC(K, XK) { float _y = bs##K; \
    _y = fmaf(e0, w##K##0, _y); _y = fmaf(e1, w##K##1, _y); _y = fmaf(e2, w##K##2, _y); \
    _y = fmaf(e3, w##K##3, _y); _y = fmaf(e4, w##K##4, _y); _y = fmaf(e5, w##K##5, _y); \
    float _t = fmaf(av##K, fmaxf(_y, 0.f), bv##K); msg = fmaf(XK, _t, msg); }

__global__ __launch_bounds__(256, 2) void k_conv(const float* __restrict__ xin,
        const float* __restrict__ ea, const int* __restrict__ src, const int* __restrict__ dst,
        const float* __restrict__ nw, const float* __restrict__ nb,
        const float* __restrict__ A, const float* __restrict__ B,
        float* __restrict__ agg) {
    const int tid = threadIdx.x;
    const int lane = tid & 63;
    const int q = tid >> 6;        // wave = i-quarter
    const int p = lane >> 5;
    const int o = lane & 31;

    CDECL(0) CDECL(1) CDECL(2) CDECL(3)
    CLOAD(0) CLOAD(1) CLOAD(2) CLOAD(3)
    CPIN(0) CPIN(1) CPIN(2) CPIN(3)

    const int step = gridDim.x;
    int e = blockIdx.x;
    int sc = 0, dc = 0;
    float e0 = 0, e1 = 0, e2 = 0, e3 = 0, e4 = 0, e5 = 0;
    float x0 = 0, x1 = 0, x2 = 0, x3 = 0;
    if (e < NE) {
        sc = src[e]; dc = dst[e];
        const float* er = ea + e * 6;
        e0 = er[0]; e1 = er[1]; e2 = er[2]; e3 = er[3]; e4 = er[4]; e5 = er[5];
        const float* xr = xin + sc * 32 + (q << 3) + p;
        x0 = xr[0]; x1 = xr[2]; x2 = xr[4]; x3 = xr[6];
    }
    while (e < NE) {
        const int en = e + step;
        int sn = 0, dn = 0;
        float n0 = 0, n1 = 0, n2 = 0, n3 = 0, n4 = 0, n5 = 0;
        float y0 = 0, y1 = 0, y2 = 0, y3 = 0;
        if (en < NE) {
            sn = src[en]; dn = dst[en];
            const float* er = ea + en * 6;
            n0 = er[0]; n1 = er[1]; n2 = er[2]; n3 = er[3]; n4 = er[4]; n5 = er[5];
            const float* xr = xin + sn * 32 + (q << 3) + p;
            y0 = xr[0]; y1 = xr[2]; y2 = xr[4]; y3 = xr[6];
        }
        float msg = 0.f;
        CACC(0, x0) CACC(1, x1) CACC(2, x2) CACC(3, x3)
        msg += __shfl_xor(msg, 32, 64);
        if (p == 0) atomicAdd(&agg[dc * 32 + o], msg);
        sc = sn; dc = dn;
        e0 = n0; e1 = n1; e2 = n2; e3 = n3; e4 = n4; e5 = n5;
        x0 = y0; x1 = y1; x2 = y2; x3 = y3;
        e = en;
    }
}

// ---------------------------------------- lin1: relu(cat(x1,x2)@W^T+b) + stats
__global__ __launch_bounds__(384) void k_lin1a(const float* __restrict__ x1,
        const float* __restrict__ x2, const float* __restrict__ lw, const float* __restrict__ lb,
        float* __restrict__ pre, float* __restrict__ gsum, float* __restrict__ gsumsq) {
    __shared__ float cat[4][64];
    __shared__ float sh_s[96], sh_ss[96];
    const int tid = threadIdx.x;
    const int np = tid / 96;   // 0..3
    const int q = tid - np * 96;
    float w[64];
#pragma unroll
    for (int k = 0; k < 64; ++k) w[k] = lw[q * 64 + k];
    const float bq = lb[q];
    float s = 0.f, ss = 0.f;
    for (int nb = blockIdx.x * 4; nb < NN; nb += gridDim.x * 4) {
        __syncthreads();
        if (tid < 256) {
            int n2 = tid >> 6, k = tid & 63;
            cat[n2][k] = (k < 32) ? x1[(nb + n2) * 32 + k] : x2[(nb + n2) * 32 + (k - 32)];
        }
        __syncthreads();
        float v = bq;
#pragma unroll
        for (int k = 0; k < 64; ++k) v = fmaf(cat[np][k], w[k], v);
        float r = fmaxf(v, 0.f);
        pre[(nb + np) * 96 + q] = r;
        s += r; ss = fmaf(r, r, ss);
    }
    __syncthreads();
    if (tid < 96) { sh_s[tid] = 0.f; sh_ss[tid] = 0.f; }
    __syncthreads();
    atomicAdd(&sh_s[q], s);
    atomicAdd(&sh_ss[q], ss);
    __syncthreads();
    if (tid < 96) {
        atomicAdd(&gsum[tid], sh_s[tid]);
        atomicAdd(&gsumsq[tid], sh_ss[tid]);
    }
}

__global__ __launch_bounds__(384) void k_lin1b(const float* __restrict__ gsum,
        const float* __restrict__ gsumsq, const float* __restrict__ g, const float* __restrict__ beta,
        const float* __restrict__ pre, float* __restrict__ xc) {
    const int tid = threadIdx.x;
    const int np = tid / 96;
    const int q = tid - np * 96;
    const float invN = 1.f / NN;
    float mean = gsum[q] * invN;
    float var = fmaxf(gsumsq[q] * invN - mean * mean, 0.f);
    float a = g[q] * rsqrtf(var + EPS);
    float b = beta[q] - mean * a;
    for (int nb = blockIdx.x * 4; nb < NN; nb += gridDim.x * 4) {
        int n = nb + np;
        xc[n * 96 + q] = fmaf(a, pre[n * 96 + q], b);
    }
}

// ------------------------------------------------- Set2Set: whole loop per graph
__global__ __launch_bounds__(512) void k_s2s(const float* __restrict__ xc,
        const int* __restrict__ batch,
        const float* __restrict__ w_ih, const float* __restrict__ w_hh,
        const float* __restrict__ b_ih, const float* __restrict__ b_hh,
        float* __restrict__ qs_g, float* __restrict__ e_ws) {
    __shared__ float qs[192], h[96], c[96], gates[384];
    __shared__ float redm[8], reds[8];
    __shared__ float racc_s[5][96];
    __shared__ float sh_scal[2];   // [0]=emax, [1]=1/asum
    __shared__ int sse[2];
    const int tid = threadIdx.x;
    const int wid = tid >> 6, lane = tid & 63;
    const int b = blockIdx.x;
    if (tid < 2) {   // inline graph-range binary search (start of graph b+tid)
        int key = b + tid, lo = 0, hi = NN;
        while (lo < hi) { int mid = (lo + hi) >> 1; if (batch[mid] < key) lo = mid + 1; else hi = mid; }
        sse[tid] = lo;
    }
    if (tid < 192) qs[tid] = 0.f;
    if (tid < 96) { h[tid] = 0.f; c[tid] = 0.f; }
    __syncthreads();
    const int s = sse[0], t = sse[1];
    for (int step = 0; step < 3; ++step) {
        if (tid < 384) {
            float acc = b_ih[tid] + b_hh[tid];
            const float* wi = &w_ih[tid * 192];
#pragma unroll 8
            for (int k = 0; k < 192; ++k) acc = fmaf(qs[k], wi[k], acc);
            const float* wh = &w_hh[tid * 96];
#pragma unroll 8
            for (int k = 0; k < 96; ++k) acc = fmaf(h[k], wh[k], acc);
            gates[tid] = acc;
        }
        __syncthreads();
        if (tid < 96) {
            float ig = 1.f / (1.f + __expf(-gates[tid]));
            float fg = 1.f / (1.f + __expf(-gates[96 + tid]));
            float gg = tanhf(gates[192 + tid]);
            float og = 1.f / (1.f + __expf(-gates[288 + tid]));
            float cn = fg * c[tid] + ig * gg;
            c[tid] = cn;
            h[tid] = og * tanhf(cn);
        }
        __syncthreads();
        float pmax = -INFINITY;
        for (int n = s + tid; n < t; n += 512) {
            const float* xr = &xc[n * 96];
            float acc = 0.f;
#pragma unroll 8
            for (int k = 0; k < 96; ++k) acc = fmaf(xr[k], h[k], acc);
            e_ws[n] = acc;
            pmax = fmaxf(pmax, acc);
        }
#pragma unroll
        for (int off = 32; off > 0; off >>= 1) pmax = fmaxf(pmax, __shfl_down(pmax, off));
        if (lane == 0) redm[wid] = pmax;
        __syncthreads();
        if (tid == 0) {
            float m = redm[0];
#pragma unroll
            for (int i = 1; i < 8; ++i) m = fmaxf(m, redm[i]);
            if (!isfinite(m)) m = 0.f;
            sh_scal[0] = m;
        }
        __syncthreads();
        const float emax = sh_scal[0];
        float pa = 0.f;
        for (int n = s + tid; n < t; n += 512) {
            float a = __expf(e_ws[n] - emax);
            e_ws[n] = a;
            pa += a;
        }
#pragma unroll
        for (int off = 32; off > 0; off >>= 1) pa += __shfl_down(pa, off);
        if (lane == 0) reds[wid] = pa;
        __syncthreads();
        if (tid == 0) {
            float a2 = 0.f;
#pragma unroll
            for (int i = 0; i < 8; ++i) a2 += reds[i];
            sh_scal[1] = (a2 > 0.f) ? 1.f / a2 : 0.f;
        }
        __syncthreads();
        const int g = tid / 96, q = tid - g * 96;
        if (tid < 480) {
            float racc = 0.f;
            for (int n = s + g; n < t; n += 5)
                racc = fmaf(e_ws[n], xc[n * 96 + q], racc);
            racc_s[g][q] = racc;
        }
        __syncthreads();
        if (tid < 96) {
            float r = (racc_s[0][tid] + racc_s[1][tid] + racc_s[2][tid]
                     + racc_s[3][tid] + racc_s[4][tid]) * sh_scal[1];
            qs[tid] = h[tid];
            qs[96 + tid] = r;
        }
        __syncthreads();
    }
    if (tid < 192) qs_g[b * 192 + tid] = qs[tid];
}

// -------------------------------- xg = qs@s2s_w^T+b ; pre_m1 = relu(xg@m1^T+b)
__global__ __launch_bounds__(128) void k_xg(const float* __restrict__ qs_g,
        const float* __restrict__ sw, const float* __restrict__ sb,
        const float* __restrict__ m1w, const float* __restrict__ m1b,
        float* __restrict__ pre, float* __restrict__ gsum, float* __restrict__ gsumsq) {
    __shared__ float xg0[96];
    const int tid = threadIdx.x;
    const int b = blockIdx.x;
    if (tid < 96) {
        const float* q = &qs_g[b * 192];
        float acc = sb[tid];
        const float* w = &sw[tid * 192];
#pragma unroll 8
        for (int k = 0; k < 192; ++k) acc = fmaf(q[k], w[k], acc);
        xg0[tid] = acc;
    }
    __syncthreads();
    if (tid < 96) {
        float acc = m1b[tid];
        const float* w = &m1w[tid * 96];
#pragma unroll 8
        for (int k = 0; k < 96; ++k) acc = fmaf(xg0[k], w[k], acc);
        float r = fmaxf(acc, 0.f);
        pre[b * 96 + tid] = r;
        atomicAdd(&gsum[tid], r);
        atomicAdd(&gsumsq[tid], r * r);
    }
}

// ----------------------------------------- tail: BN(m1) -> m2 linear+relu+BN
__global__ __launch_bounds__(256) void k_tail(const float* __restrict__ pre,
        const float* __restrict__ gsum, const float* __restrict__ gsumsq,
        const float* __restrict__ g1, const float* __restrict__ beta1,
        const float* __restrict__ m2w, const float* __restrict__ m2b,
        const float* __restrict__ g2, const float* __restrict__ beta2,
        float* __restrict__ out) {
    __shared__ float xg1[100][97];
    __shared__ float pre2[200];
    __shared__ float ab2[4];
    const int tid = threadIdx.x;
    if (tid < 96) {
        const float invN = 1.f / NG;
        float mean = gsum[tid] * invN;
        float var = fmaxf(gsumsq[tid] * invN - mean * mean, 0.f);
        float a = g1[tid] * rsqrtf(var + EPS);
        float bb = beta1[tid] - mean * a;
        for (int n = 0; n < NG; ++n)
            xg1[n][tid] = fmaf(a, pre[n * 96 + tid], bb);
    }
    __syncthreads();
    if (tid < 200) {
        int n = tid >> 1, cc = tid & 1;
        float acc = m2b[cc];
        const float* w = &m2w[cc * 96];
#pragma unroll 8
        for (int k = 0; k < 96; ++k) acc = fmaf(xg1[n][k], w[k], acc);
        pre2[tid] = fmaxf(acc, 0.f);
    }
    __syncthreads();
    if (tid < 2) {
        float s = 0.f, ss = 0.f;
        for (int n = 0; n < NG; ++n) { float v = pre2[n * 2 + tid]; s += v; ss = fmaf(v, v, ss); }
        const float invN = 1.f / NG;
        float mean = s * invN;
        float var = fmaxf(ss * invN - mean * mean, 0.f);
        float a = g2[tid] * rsqrtf(var + EPS);
        ab2[tid] = a;
        ab2[2 + tid] = beta2[tid] - mean * a;
    }
    __syncthreads();
    if (tid < 200) {
        int cc = tid & 1;
        out[tid] = fmaf(ab2[cc], pre2[tid], ab2[2 + cc]);
    }
}

extern "C" void kernel_launch(void* const* d_in, const int* in_sizes, int n_in,
                              void* d_out, int out_size, void* d_ws, size_t ws_size,
                              hipStream_t stream) {
    (void)in_sizes; (void)n_in; (void)out_size; (void)ws_size;
    const float* x       = (const float*)d_in[0];
    const float* ea      = (const float*)d_in[1];
    const float* c1w     = (const float*)d_in[2];
    const float* c1b     = (const float*)d_in[3];
    const float* c1g     = (const float*)d_in[4];
    const float* c1beta  = (const float*)d_in[5];
    const float* c1root  = (const float*)d_in[6];
    const float* c1bias  = (const float*)d_in[7];
    const float* c2w     = (const float*)d_in[8];
    const float* c2b     = (const float*)d_in[9];
    const float* c2g     = (const float*)d_in[10];
    const float* c2beta  = (const float*)d_in[11];
    const float* c2root  = (const float*)d_in[12];
    const float* c2bias  = (const float*)d_in[13];
    const float* lin1w   = (const float*)d_in[14];
    const float* lin1b   = (const float*)d_in[15];
    const float* lin1g   = (const float*)d_in[16];
    const float* lin1bt  = (const float*)d_in[17];
    const float* wih     = (const float*)d_in[18];
    const float* whh     = (const float*)d_in[19];
    const float* bih     = (const float*)d_in[20];
    const float* bhh     = (const float*)d_in[21];
    const float* s2sw    = (const float*)d_in[22];
    const float* s2sb    = (const float*)d_in[23];
    const float* m1w     = (const float*)d_in[24];
    const float* m1b     = (const float*)d_in[25];
    const float* m1g     = (const float*)d_in[26];
    const float* m1beta  = (const float*)d_in[27];
    const float* m2w     = (const float*)d_in[28];
    const float* m2b     = (const float*)d_in[29];
    const float* m2g     = (const float*)d_in[30];
    const float* m2beta  = (const float*)d_in[31];
    const int* src       = (const int*)d_in[32];
    const int* dst       = (const int*)d_in[33];
    const int* batch     = (const int*)d_in[34];

    float* ws = (float*)d_ws;
    float* stats  = ws;                 // 4096
    float* AB     = ws + 4096;          // 4096: A1|B1|A2|B2
    float* linst  = ws + 8192;          // 192
    float* m1st   = ws + 8384;          // 192
    float* x1     = ws + 8704;          // 320000
    float* x2     = x1 + 320000;        // 320000
    float* prelin = x2 + 320000;        // 960000 (BN in-place -> xc)
    float* e_ws   = prelin + 960000;    // 10000
    float* qs_g   = e_ws + 10000;       // 19200
    float* prem1  = qs_g + 19200;       // 9600

    hipMemsetAsync(ws, 0, 8576 * sizeof(float), stream);

    // ---- fused BN stats for both convs (float2-paired cols, LDS-staged ea)
    k_stats4<<<1250, 512, 0, stream>>>(ea, c1w, c1b, c2w, c2b, stats);

    // ---- conv1 (root1 also computes both convs' BN affines in its last block)
    k_root<<<1251, 256, 0, stream>>>(x, c1root, c1bias, x1,
                                     1, stats, c1g, c1beta, c2g, c2beta, AB);
    k_conv<<<2048, 256, 0, stream>>>(x, ea, src, dst, c1w, c1b, AB, AB + 1024, x1);

    // ---- conv2
    k_root<<<1250, 256, 0, stream>>>(x1, c2root, c2bias, x2,
                                     0, stats, c1g, c1beta, c2g, c2beta, AB);
    k_conv<<<2048, 256, 0, stream>>>(x1, ea, src, dst, c2w, c2b, AB + 2048, AB + 3072, x2);

    // ---- lin1 (Linear+ReLU+BN)
    k_lin1a<<<500, 384, 0, stream>>>(x1, x2, lin1w, lin1b, prelin, linst, linst + 96);
    k_lin1b<<<500, 384, 0, stream>>>(linst, linst + 96, lin1g, lin1bt, prelin, prelin);

    // ---- Set2Set (graph ranges found in-kernel)
    k_s2s<<<100, 512, 0, stream>>>(prelin, batch, wih, whh, bih, bhh, qs_g, e_ws);

    // ---- tail MLPs
    k_xg<<<100, 128, 0, stream>>>(qs_g, s2sw, s2sb, m1w, m1b, prem1, m1st, m1st + 96);
    k_tail<<<1, 256, 0, stream>>>(prem1, m1st, m1st + 96, m1g, m1beta,
                                  m2w, m2b, m2g, m2beta, (float*)d_out);
}